// Round 1
// 272.469 us; speedup vs baseline: 1.0555x; 1.0555x over previous
//
#include <hip/hip_runtime.h>
#include <math.h>

// Problem constants (reference: B=1, N=64, Q=K=512, C_Q=C_K=C_V=256, H=8, c=32)
#define NSEQ   64
#define QLEN   512
#define KLEN   512
#define CIN    256
#define HEADS  8
#define CH     32
#define HIDDIM 256
#define M_TOTAL (NSEQ * QLEN)   // 32768 rows for all projections

typedef _Float16 f16x8 __attribute__((ext_vector_type(8)));
typedef _Float16 f16x4 __attribute__((ext_vector_type(4)));
typedef __fp16   fp16x2 __attribute__((ext_vector_type(2)));   // cvt_pkrtz native type
typedef float    f32x4 __attribute__((ext_vector_type(4)));

// Async global->LDS, 16B per lane. Dest must be linear in lane order
// (wave-uniform base + lane*16); swizzling is done on the GLOBAL source
// address and mirrored on the LDS read side (guide G21: both-sides-or-neither).
__device__ __forceinline__ void gload16(const void* g, void* l) {
    __builtin_amdgcn_global_load_lds(
        (const __attribute__((address_space(1))) void*)g,
        (__attribute__((address_space(3))) void*)l, 16, 0, 0);
}

// ---------------------------------------------------------------------------
// Weight transpose+cast: W[256 in][256 out] fp32 -> WT[256 out][256 in] fp16.
// Slab order: 0=wq, 1=wg, 2=wk, 3=wv, 4=wo  (q and g adjacent for fused proj).
// ---------------------------------------------------------------------------
__global__ __launch_bounds__(256) void wcast_kernel(
    const float* __restrict__ w0, const float* __restrict__ w1,
    const float* __restrict__ w2, const float* __restrict__ w3,
    const float* __restrict__ w4, _Float16* __restrict__ wt)
{
    __shared__ float t[64][65];
    const float* W;
    switch (blockIdx.z) {
        case 0: W = w0; break; case 1: W = w1; break;
        case 2: W = w2; break; case 3: W = w3; break;
        default: W = w4;
    }
    _Float16* WT = wt + (size_t)blockIdx.z * 65536;
    const int i0 = blockIdx.x * 64, o0 = blockIdx.y * 64;
    const int tid = threadIdx.x;
    const int rr = tid >> 4, c4 = tid & 15;
    #pragma unroll
    for (int i = 0; i < 4; ++i) {
        const int row = rr + i * 16;
        *(float4*)&t[row][c4 * 4] = *(const float4*)&W[(size_t)(i0 + row) * 256 + o0 + c4 * 4];
    }
    __syncthreads();
    #pragma unroll
    for (int i = 0; i < 4; ++i) {
        const int row = rr + i * 16;            // out-dim row
        f16x4 v;
        #pragma unroll
        for (int j = 0; j < 4; ++j) v[j] = (_Float16)t[c4 * 4 + j][row];
        *(f16x4*)&WT[(size_t)(o0 + row) * 256 + i0 + c4 * 4] = v;
    }
}

// ---------------------------------------------------------------------------
// bias_pair -> MFMA-fragment order (unchanged):
// bp_frag[((h*32+qt)*32+kt)*256 + lane*4 + reg] = bias_pair[h][qt*16+l15][kt*16+quad*4+reg]
// ---------------------------------------------------------------------------
__global__ __launch_bounds__(256) void bpfrag_kernel(
    const float* __restrict__ bias_pair, float* __restrict__ frag)
{
    __shared__ float t[64][68];
    const int qb = blockIdx.x, kb = blockIdx.y, h = blockIdx.z;
    const int tid = threadIdx.x;
    #pragma unroll
    for (int i = 0; i < 4; ++i) {
        const int idx = tid + i * 256;
        const int r = idx >> 4, c4 = idx & 15;
        *(float4*)&t[r][c4 * 4] = *(const float4*)
            &bias_pair[((size_t)h * QLEN + qb * 64 + r) * KLEN + kb * 64 + c4 * 4];
    }
    __syncthreads();
    const int lane = tid & 63, w = tid >> 6;
    const int l15 = lane & 15, quad = lane >> 4;
    const int qt = qb * 4 + w;
    #pragma unroll
    for (int kt2 = 0; kt2 < 4; ++kt2) {
        const int kt = kb * 4 + kt2;
        float4 v;
        v.x = t[w * 16 + l15][kt2 * 16 + quad * 4 + 0];
        v.y = t[w * 16 + l15][kt2 * 16 + quad * 4 + 1];
        v.z = t[w * 16 + l15][kt2 * 16 + quad * 4 + 2];
        v.w = t[w * 16 + l15][kt2 * 16 + quad * 4 + 3];
        *(float4*)&frag[(((size_t)(h * 32 + qt) * 32) + kt) * 256 + lane * 4] = v;
    }
}

// ---------------------------------------------------------------------------
// Fused projection GEMM, software-pipelined.
// Grid (256, 4, 2); mode = (z<<1)|(y>>1): 0=q (scale), 1=g (sigmoid+bg),
// 2=k, 3=v (written directly in vT[(n*8+h)*32+c][k] layout -> vtrans deleted).
// Pipeline per K-step: issue A loads (regs) + B tile (async global_load_lds,
// double-buffered, XOR-swizzled) -> MFMA current step -> barrier (vmcnt drain
// lands AFTER compute) -> cvt+ds_write A -> barrier.
// B_s linear [128][64] fp16: chunk swizzle pc = lc ^ (row&7) applied on the
// global source and on the ds_read -> conflict-free ds_read_b128.
// launch_bounds(256,2): 32 in-flight staging VGPRs need >128 total regs;
// occupancy is LDS-bound at 3 blocks/CU (50 KB) regardless.
// ---------------------------------------------------------------------------
__global__ __launch_bounds__(256, 2) void proj_gemm_kernel(
    const float* __restrict__ q_x, const float* __restrict__ k_x,
    const float* __restrict__ v_x, const _Float16* __restrict__ wT,
    const float* __restrict__ bg,
    _Float16* __restrict__ oq, _Float16* __restrict__ ok,
    _Float16* __restrict__ ovT, _Float16* __restrict__ og)
{
    __shared__ _Float16 A_s[128][72];            // padded, reg-staged (fp32 cvt)
    __shared__ __attribute__((aligned(16))) _Float16 B_s[2][128 * 64];  // linear, gload_lds

    const int mode = (blockIdx.z << 1) | (blockIdx.y >> 1);
    const float* A = (mode <= 1) ? q_x : (mode == 2) ? k_x : v_x;
    const _Float16* BT = wT + (size_t)mode * 65536;
    const int m0 = blockIdx.x * 128;
    const int n0 = (blockIdx.y & 1) * 128;
    const int tid = threadIdx.x;
    const int lane = tid & 63, w = tid >> 6;
    const int l15 = lane & 15, quad = lane >> 4;
    const int mw = (w & 1) * 64, nw = (w >> 1) * 64;
    const int ar = tid >> 3, aseg = tid & 7;     // A staging: rows ar+32*it, 8 floats

    f32x4 acc[4][4];
    #pragma unroll
    for (int mt = 0; mt < 4; ++mt)
        #pragma unroll
        for (int nt = 0; nt < 4; ++nt) acc[mt][nt] = (f32x4){0.f, 0.f, 0.f, 0.f};

    float4 alo[4], ahi[4];
    // ---- prologue: stage K-step 0 ----
    #pragma unroll
    for (int it = 0; it < 4; ++it) {
        const float* ap = A + (size_t)(m0 + ar + it * 32) * CIN + aseg * 8;
        alo[it] = *(const float4*)ap;
        ahi[it] = *(const float4*)(ap + 4);
    }
    #pragma unroll
    for (int j = 0; j < 4; ++j) {
        const int p = tid + j * 256;             // 16B chunk id 0..1023
        const int r = p >> 3;
        const int lc = (p & 7) ^ (r & 7);        // logical chunk (inverse swizzle)
        gload16(BT + (size_t)(n0 + r) * CIN + lc * 8, &B_s[0][p * 8]);
    }
    #pragma unroll
    for (int it = 0; it < 4; ++it) {
        f16x8 v;
        v[0] = (_Float16)alo[it].x; v[1] = (_Float16)alo[it].y;
        v[2] = (_Float16)alo[it].z; v[3] = (_Float16)alo[it].w;
        v[4] = (_Float16)ahi[it].x; v[5] = (_Float16)ahi[it].y;
        v[6] = (_Float16)ahi[it].z; v[7] = (_Float16)ahi[it].w;
        *(f16x8*)&A_s[ar + it * 32][aseg * 8] = v;
    }
    __syncthreads();                             // drains vmcnt -> B(0) in LDS

    int buf = 0;
    for (int kk = 0; kk < 4; ++kk) {
        if (kk < 3) {
            const int k0n = (kk + 1) * 64;
            // issue next A loads + next B tile BEFORE computing this step
            #pragma unroll
            for (int it = 0; it < 4; ++it) {
                const float* ap = A + (size_t)(m0 + ar + it * 32) * CIN + k0n + aseg * 8;
                alo[it] = *(const float4*)ap;
                ahi[it] = *(const float4*)(ap + 4);
            }
            #pragma unroll
            for (int j = 0; j < 4; ++j) {
                const int p = tid + j * 256;
                const int r = p >> 3;
                const int lc = (p & 7) ^ (r & 7);
                gload16(BT + (size_t)(n0 + r) * CIN + k0n + lc * 8, &B_s[buf ^ 1][p * 8]);
            }
        }
        #pragma unroll
        for (int ks = 0; ks < 2; ++ks) {
            f16x8 af[4], bf[4];
            #pragma unroll
            for (int mt = 0; mt < 4; ++mt)
                af[mt] = *(const f16x8*)&A_s[mw + mt * 16 + l15][ks * 32 + quad * 8];
            #pragma unroll
            for (int nt = 0; nt < 4; ++nt) {
                const int brow = nw + nt * 16 + l15;
                const int bc = (ks * 4 + quad) ^ (brow & 7);   // swizzled read
                bf[nt] = *(const f16x8*)&B_s[buf][brow * 64 + bc * 8];
            }
            #pragma unroll
            for (int mt = 0; mt < 4; ++mt)
                #pragma unroll
                for (int nt = 0; nt < 4; ++nt)
                    acc[mt][nt] = __builtin_amdgcn_mfma_f32_16x16x32_f16(
                        af[mt], bf[nt], acc[mt][nt], 0, 0, 0);
        }
        if (kk < 3) {
            __syncthreads();                     // A_s reads done; loads drained
            #pragma unroll
            for (int it = 0; it < 4; ++it) {
                f16x8 v;
                v[0] = (_Float16)alo[it].x; v[1] = (_Float16)alo[it].y;
                v[2] = (_Float16)alo[it].z; v[3] = (_Float16)alo[it].w;
                v[4] = (_Float16)ahi[it].x; v[5] = (_Float16)ahi[it].y;
                v[6] = (_Float16)ahi[it].z; v[7] = (_Float16)ahi[it].w;
                *(f16x8*)&A_s[ar + it * 32][aseg * 8] = v;
            }
            __syncthreads();                     // next A tile visible
            buf ^= 1;
        }
    }

    // Epilogue by mode. v-mode: acc regs are 4 consecutive q-rows = consecutive
    // k positions -> contiguous f16x4 store directly into vT layout.
    #pragma unroll
    for (int mt = 0; mt < 4; ++mt) {
        #pragma unroll
        for (int nt = 0; nt < 4; ++nt) {
            const int col = n0 + nw + nt * 16 + l15;
            const int rowb = m0 + mw + mt * 16 + quad * 4;
            if (mode == 3) {
                const int nn = rowb >> 9, kpos = rowb & 511;
                f16x4 st;
                #pragma unroll
                for (int reg = 0; reg < 4; ++reg) st[reg] = (_Float16)acc[mt][nt][reg];
                *(f16x4*)&ovT[((size_t)(nn * 256 + col)) * 512 + kpos] = st;
            } else {
                _Float16* C = (mode == 0) ? oq : (mode == 1) ? og : ok;
                #pragma unroll
                for (int reg = 0; reg < 4; ++reg) {
                    float x = acc[mt][nt][reg];
                    if (mode == 0) x *= 0.17677669529663689f;
                    if (mode == 1) { x += bg[col]; x = 1.0f / (1.0f + __expf(-x)); }
                    C[(size_t)(rowb + reg) * HIDDIM + col] = (_Float16)x;
                }
            }
        }
    }
}

// ---------------------------------------------------------------------------
// Output projection GEMM (fp16 in, fp32 out + bias). Both operands staged via
// async global_load_lds, double-buffered, ONE barrier per K-step.
// LDS 64 KB -> 2 blocks/CU; launch_bounds(256,2) matches.
// ---------------------------------------------------------------------------
__global__ __launch_bounds__(256, 2) void gemm_mfma_kernel(
    const _Float16* __restrict__ Ain, const _Float16* __restrict__ BT,
    const float* __restrict__ bias, float* __restrict__ Cout)
{
    __shared__ __attribute__((aligned(16))) _Float16 A_s[2][128 * 64];
    __shared__ __attribute__((aligned(16))) _Float16 B_s[2][128 * 64];
    const int m0 = blockIdx.x * 128, n0 = blockIdx.y * 128;
    const int tid = threadIdx.x;
    const int lane = tid & 63, w = tid >> 6;
    const int l15 = lane & 15, quad = lane >> 4;
    const int mw = (w & 1) * 64, nw = (w >> 1) * 64;

    f32x4 acc[4][4];
    #pragma unroll
    for (int mt = 0; mt < 4; ++mt)
        #pragma unroll
        for (int nt = 0; nt < 4; ++nt) acc[mt][nt] = (f32x4){0.f, 0.f, 0.f, 0.f};

    #pragma unroll
    for (int j = 0; j < 4; ++j) {
        const int p = tid + j * 256;
        const int r = p >> 3;
        const int lc = (p & 7) ^ (r & 7);
        gload16(Ain + (size_t)(m0 + r) * CIN + lc * 8, &A_s[0][p * 8]);
        gload16(BT  + (size_t)(n0 + r) * CIN + lc * 8, &B_s[0][p * 8]);
    }
    __syncthreads();

    int buf = 0;
    for (int kk = 0; kk < 4; ++kk) {
        if (kk < 3) {
            const int k0n = (kk + 1) * 64;
            #pragma unroll
            for (int j = 0; j < 4; ++j) {
                const int p = tid + j * 256;
                const int r = p >> 3;
                const int lc = (p & 7) ^ (r & 7);
                gload16(Ain + (size_t)(m0 + r) * CIN + k0n + lc * 8, &A_s[buf ^ 1][p * 8]);
                gload16(BT  + (size_t)(n0 + r) * CIN + k0n + lc * 8, &B_s[buf ^ 1][p * 8]);
            }
        }
        #pragma unroll
        for (int ks = 0; ks < 2; ++ks) {
            f16x8 af[4], bf[4];
            #pragma unroll
            for (int mt = 0; mt < 4; ++mt) {
                const int arow = mw + mt * 16 + l15;
                const int ac = (ks * 4 + quad) ^ (arow & 7);
                af[mt] = *(const f16x8*)&A_s[buf][arow * 64 + ac * 8];
            }
            #pragma unroll
            for (int nt = 0; nt < 4; ++nt) {
                const int brow = nw + nt * 16 + l15;
                const int bc = (ks * 4 + quad) ^ (brow & 7);
                bf[nt] = *(const f16x8*)&B_s[buf][brow * 64 + bc * 8];
            }
            #pragma unroll
            for (int mt = 0; mt < 4; ++mt)
                #pragma unroll
                for (int nt = 0; nt < 4; ++nt)
                    acc[mt][nt] = __builtin_amdgcn_mfma_f32_16x16x32_f16(
                        af[mt], bf[nt], acc[mt][nt], 0, 0, 0);
        }
        if (kk < 3) { __syncthreads(); buf ^= 1; }
    }

    #pragma unroll
    for (int mt = 0; mt < 4; ++mt) {
        #pragma unroll
        for (int nt = 0; nt < 4; ++nt) {
            const int col = n0 + nw + nt * 16 + l15;
            const int rowb = m0 + mw + mt * 16 + quad * 4;
            #pragma unroll
            for (int reg = 0; reg < 4; ++reg) {
                const float x = acc[mt][nt][reg] + bias[col];
                Cout[(size_t)(rowb + reg) * HIDDIM + col] = x;
            }
        }
    }
}

// ---------------------------------------------------------------------------
// MFMA flash attention — UNCHANGED from the 287.6 us version.
// ---------------------------------------------------------------------------
__global__ __launch_bounds__(256, 4) void attn_kernel(
    const _Float16* __restrict__ qb, const _Float16* __restrict__ kb,
    const _Float16* __restrict__ vT, const _Float16* __restrict__ gb,
    _Float16* __restrict__ ob,
    const float* __restrict__ bias_mask, const float* __restrict__ bp_frag)
{
    __shared__ _Float16 k_s[128][40];    // 80B rows ≡ 20 banks mod 32
    __shared__ _Float16 v_s[32][136];    // [c][k], 272B rows ≡ 4 banks mod 32

    const int n    = blockIdx.x;
    const int h    = blockIdx.y;
    const int q0   = blockIdx.z * 128;
    const int tid  = threadIdx.x;
    const int lane = tid & 63;
    const int wq   = tid >> 6;            // wave id: q-band = wq*32
    const int l15  = lane & 15;
    const int quad = lane >> 4;

    f16x8 qf[2];
    #pragma unroll
    for (int qt = 0; qt < 2; ++qt)
        qf[qt] = *(const f16x8*)(qb +
            (size_t)(n * QLEN + q0 + wq * 32 + qt * 16 + l15) * HIDDIM + h * CH + quad * 8);

    const float* bpf = bp_frag +
        ((size_t)(h * 32 + blockIdx.z * 8 + wq * 2) * 32) * 256 + lane * 4;
    const float* bmb = bias_mask + n * KLEN + quad * 4;

    f32x4 o_acc[2][2];
    float l_lane[2] = {0.f, 0.f};
    #pragma unroll
    for (int qt = 0; qt < 2; ++qt)
        #pragma unroll
        for (int ct = 0; ct < 2; ++ct) o_acc[qt][ct] = (f32x4){0.f, 0.f, 0.f, 0.f};

    const f32x4 z4 = (f32x4){0.f, 0.f, 0.f, 0.f};

    for (int ch = 0; ch < 4; ++ch) {
        __syncthreads();
        #pragma unroll
        for (int i = 0; i < 2; ++i) {
            const int idx = tid + i * 256;
            const int r = idx >> 2, c8 = idx & 3;
            *(uint4*)&k_s[r][c8 * 8] = *(const uint4*)
                (kb + (size_t)(n * KLEN + ch * 128 + r) * HIDDIM + h * CH + c8 * 8);
            const int vr = idx >> 4, vs = idx & 15;
            *(uint4*)&v_s[vr][vs * 8] = *(const uint4*)
                (vT + ((size_t)(n * HEADS + h) * CH + vr) * KLEN + ch * 128 + vs * 8);
        }
        __syncthreads();

        #pragma unroll
        for (int kt = 0; kt < 8; ++kt) {
            const int kti = ch * 8 + kt;
            const f16x8 kf = *(const f16x8*)&k_s[kt * 16 + l15][quad * 8];
            const f32x4 s0 = __builtin_amdgcn_mfma_f32_16x16x32_f16(kf, qf[0], z4, 0, 0, 0);
            const f32x4 s1 = __builtin_amdgcn_mfma_f32_16x16x32_f16(kf, qf[1], z4, 0, 0, 0);
            const float4 bm = *(const float4*)(bmb + ch * 128 + kt * 16);
            const f16x4 bv0 = *(const f16x4*)&v_s[l15][kt * 16 + quad * 4];
            const f16x4 bv1 = *(const f16x4*)&v_s[16 + l15][kt * 16 + quad * 4];
            #pragma unroll
            for (int qt = 0; qt < 2; ++qt) {
                const f32x4 s = qt ? s1 : s0;
                const float4 bp = *(const float4*)(bpf + ((size_t)qt * 32 + kti) * 256);
                const float p0 = __expf(s[0] + bm.x + bp.x - 4.0f);
                const float p1 = __expf(s[1] + bm.y + bp.y - 4.0f);
                const float p2 = __expf(s[2] + bm.z + bp.z - 4.0f);
                const float p3 = __expf(s[3] + bm.w + bp.w - 4.0f);
                l_lane[qt] += (p0 + p1) + (p2 + p3);
                union { f16x4 v; fp16x2 h[2]; } u;
                u.h[0] = __builtin_amdgcn_cvt_pkrtz(p0, p1);
                u.h[1] = __builtin_amdgcn_cvt_pkrtz(p2, p3);
                o_acc[qt][0] = __builtin_amdgcn_mfma_f32_16x16x16f16(u.v, bv0, o_acc[qt][0], 0, 0, 0);
                o_acc[qt][1] = __builtin_amdgcn_mfma_f32_16x16x16f16(u.v, bv1, o_acc[qt][1], 0, 0, 0);
            }
        }
    }

    float invl[2][4];
    #pragma unroll
    for (int qt = 0; qt < 2; ++qt) {
        float lf = l_lane[qt];
        lf += __shfl_xor(lf, 16);
        lf += __shfl_xor(lf, 32);
        #pragma unroll
        for (int reg = 0; reg < 4; ++reg)
            invl[qt][reg] = 1.0f / __shfl(lf, quad * 4 + reg);
    }

    #pragma unroll
    for (int qt = 0; qt < 2; ++qt) {
        #pragma unroll
        for (int ct = 0; ct < 2; ++ct) {
            #pragma unroll
            for (int reg = 0; reg < 4; ++reg) {
                const int row = q0 + wq * 32 + qt * 16 + quad * 4 + reg;
                const size_t idx = (size_t)(n * QLEN + row) * HIDDIM + h * CH + ct * 16 + l15;
                const float g = (float)gb[idx];
                ob[idx] = (_Float16)(o_acc[qt][ct][reg] * invl[qt][reg] * g);
            }
        }
    }
}

// ---------------------------------------------------------------------------
// Launch: wcast + bpfrag -> fused projections (q,g,k,v->vT) -> attention ->
// output GEMM. vtrans eliminated (proj writes vT directly).
// Workspace: 5 x 16.8 MB fp16 + 0.66 MB weights + 8.4 MB bp_frag ≈ 93 MB
// ---------------------------------------------------------------------------
extern "C" void kernel_launch(void* const* d_in, const int* in_sizes, int n_in,
                              void* d_out, int out_size, void* d_ws, size_t ws_size,
                              hipStream_t stream)
{
    const float* q_x       = (const float*)d_in[0];
    const float* k_x       = (const float*)d_in[1];
    const float* v_x       = (const float*)d_in[2];
    const float* bias_mask = (const float*)d_in[3];
    const float* bias_pair = (const float*)d_in[4];
    const float* wq        = (const float*)d_in[5];
    const float* wk        = (const float*)d_in[6];
    const float* wv        = (const float*)d_in[7];
    const float* wg        = (const float*)d_in[8];
    const float* bg        = (const float*)d_in[9];
    const float* wo        = (const float*)d_in[10];
    const float* bo        = (const float*)d_in[11];
    float* out = (float*)d_out;

    const size_t BUF = (size_t)M_TOTAL * HIDDIM;   // 8388608 elems
    _Float16* ws_q  = (_Float16*)d_ws;
    _Float16* ws_k  = ws_q + BUF;
    _Float16* ws_vT = ws_k + BUF;
    _Float16* ws_g  = ws_vT + BUF;
    _Float16* ws_o  = ws_g + BUF;
    _Float16* wT    = ws_o + BUF;                  // 5 x 256*256 fp16
    float*    bpf   = (float*)(wT + 5 * 65536);    // 8 x 512 x 512 fp32 frag-ordered

    // slab order q, g, k, v, o
    wcast_kernel<<<dim3(4, 4, 5), 256, 0, stream>>>(wq, wg, wk, wv, wo, wT);
    bpfrag_kernel<<<dim3(8, 8, 8), 256, 0, stream>>>(bias_pair, bpf);

    proj_gemm_kernel<<<dim3(M_TOTAL / 128, 4, 2), 256, 0, stream>>>(
        q_x, k_x, v_x, wT, bg, ws_q, ws_k, ws_vT, ws_g);

    attn_kernel<<<dim3(NSEQ, HEADS, QLEN / 128), 256, 0, stream>>>(
        ws_q, ws_k, ws_vT, ws_g, ws_o, bias_mask, bpf);

    gemm_mfma_kernel<<<dim3(M_TOTAL / 128, 2), 256, 0, stream>>>(
        ws_o, wT + 4 * 65536, bo, out);
}

// Round 2
// 263.684 us; speedup vs baseline: 1.0907x; 1.0333x over previous
//
#include <hip/hip_runtime.h>
#include <math.h>

// Problem constants (reference: B=1, N=64, Q=K=512, C_Q=C_K=C_V=256, H=8, c=32)
#define NSEQ   64
#define QLEN   512
#define KLEN   512
#define CIN    256
#define HEADS  8
#define CH     32
#define HIDDIM 256
#define M_TOTAL (NSEQ * QLEN)   // 32768 rows for all projections

typedef _Float16 f16x8 __attribute__((ext_vector_type(8)));
typedef _Float16 f16x4 __attribute__((ext_vector_type(4)));
typedef __fp16   fp16x2 __attribute__((ext_vector_type(2)));   // cvt_pkrtz native type
typedef float    f32x4 __attribute__((ext_vector_type(4)));

// Async global->LDS, 16B per lane. Dest must be linear in lane order
// (wave-uniform base + lane*16); swizzling is done on the GLOBAL source
// address and mirrored on the LDS read side (guide G21: both-sides-or-neither).
__device__ __forceinline__ void gload16(const void* g, void* l) {
    __builtin_amdgcn_global_load_lds(
        (const __attribute__((address_space(1))) void*)g,
        (__attribute__((address_space(3))) void*)l, 16, 0, 0);
}

// ---------------------------------------------------------------------------
// Weight transpose+cast: W[256 in][256 out] fp32 -> WT[256 out][256 in] fp16.
// Slab order: 0=wq, 1=wg, 2=wk, 3=wv, 4=wo.
// ---------------------------------------------------------------------------
__global__ __launch_bounds__(256) void wcast_kernel(
    const float* __restrict__ w0, const float* __restrict__ w1,
    const float* __restrict__ w2, const float* __restrict__ w3,
    const float* __restrict__ w4, _Float16* __restrict__ wt)
{
    __shared__ float t[64][65];
    const float* W;
    switch (blockIdx.z) {
        case 0: W = w0; break; case 1: W = w1; break;
        case 2: W = w2; break; case 3: W = w3; break;
        default: W = w4;
    }
    _Float16* WT = wt + (size_t)blockIdx.z * 65536;
    const int i0 = blockIdx.x * 64, o0 = blockIdx.y * 64;
    const int tid = threadIdx.x;
    const int rr = tid >> 4, c4 = tid & 15;
    #pragma unroll
    for (int i = 0; i < 4; ++i) {
        const int row = rr + i * 16;
        *(float4*)&t[row][c4 * 4] = *(const float4*)&W[(size_t)(i0 + row) * 256 + o0 + c4 * 4];
    }
    __syncthreads();
    #pragma unroll
    for (int i = 0; i < 4; ++i) {
        const int row = rr + i * 16;            // out-dim row
        f16x4 v;
        #pragma unroll
        for (int j = 0; j < 4; ++j) v[j] = (_Float16)t[c4 * 4 + j][row];
        *(f16x4*)&WT[(size_t)(o0 + row) * 256 + i0 + c4 * 4] = v;
    }
}

// ---------------------------------------------------------------------------
// bias_pair -> MFMA-fragment order (unchanged):
// bp_frag[((h*32+qt)*32+kt)*256 + lane*4 + reg] = bias_pair[h][qt*16+l15][kt*16+quad*4+reg]
// ---------------------------------------------------------------------------
__global__ __launch_bounds__(256) void bpfrag_kernel(
    const float* __restrict__ bias_pair, float* __restrict__ frag)
{
    __shared__ float t[64][68];
    const int qb = blockIdx.x, kb = blockIdx.y, h = blockIdx.z;
    const int tid = threadIdx.x;
    #pragma unroll
    for (int i = 0; i < 4; ++i) {
        const int idx = tid + i * 256;
        const int r = idx >> 4, c4 = idx & 15;
        *(float4*)&t[r][c4 * 4] = *(const float4*)
            &bias_pair[((size_t)h * QLEN + qb * 64 + r) * KLEN + kb * 64 + c4 * 4];
    }
    __syncthreads();
    const int lane = tid & 63, w = tid >> 6;
    const int l15 = lane & 15, quad = lane >> 4;
    const int qt = qb * 4 + w;
    #pragma unroll
    for (int kt2 = 0; kt2 < 4; ++kt2) {
        const int kt = kb * 4 + kt2;
        float4 v;
        v.x = t[w * 16 + l15][kt2 * 16 + quad * 4 + 0];
        v.y = t[w * 16 + l15][kt2 * 16 + quad * 4 + 1];
        v.z = t[w * 16 + l15][kt2 * 16 + quad * 4 + 2];
        v.w = t[w * 16 + l15][kt2 * 16 + quad * 4 + 3];
        *(float4*)&frag[(((size_t)(h * 32 + qt) * 32) + kt) * 256 + lane * 4] = v;
    }
}

// ---------------------------------------------------------------------------
// Flatmm-style fused projection GEMM.
// Grid: 512 blocks x 256 threads. combo = blockIdx.x>>6 (8): mode = combo>>1
// (0=q, 1=g, 2=k, 3=v->vT), nhalf = combo&1. Each wave holds its 32 output
// cols x K=256 of B IN REGISTERS (bfr[2][8] f16x8 = 64 VGPR, loaded once,
// L2-hot). A (fp32) streams through a double-buffered LDS panel of 32 rows
// (2 x 32 KB = 64 KB -> 2 blocks/CU) via async global_load_lds with a
// XOR-pre-swizzled source; fragment reads apply the mirrored swizzle and fuse
// the fp32->fp16 cvt. ONE barrier per panel; next-panel loads are issued
// before compute so the vmcnt(0) drain at the barrier overlaps ~400cy of
// ds_read/cvt/MFMA/store instead of stalling cold.
// ---------------------------------------------------------------------------
__global__ __launch_bounds__(256, 2) void proj_gemm_kernel(
    const float* __restrict__ q_x, const float* __restrict__ k_x,
    const float* __restrict__ v_x, const _Float16* __restrict__ wT,
    const float* __restrict__ bg,
    _Float16* __restrict__ oq, _Float16* __restrict__ ok,
    _Float16* __restrict__ ovT, _Float16* __restrict__ og)
{
    __shared__ __attribute__((aligned(16))) float A_s[2][32 * 256];  // 64 KB

    const int combo = blockIdx.x >> 6;         // 0..7
    const int blk   = blockIdx.x & 63;
    const int mode  = combo >> 1;              // 0=q,1=g,2=k,3=v
    const int nhalf = combo & 1;
    const float* A = (mode <= 1) ? q_x : (mode == 2) ? k_x : v_x;
    const _Float16* BT = wT + (size_t)mode * 65536;

    const int tid  = threadIdx.x;
    const int lane = tid & 63, w = tid >> 6;
    const int l15  = lane & 15, quad = lane >> 4;
    const int nw   = nhalf * 128 + w * 32;     // wave's 32-col base in [0,256)

    // B resident in VGPRs: bfr[nt][ks] covers col = nw+nt*16+l15, k = ks*32+quad*8..+7
    f16x8 bfr[2][8];
    #pragma unroll
    for (int nt = 0; nt < 2; ++nt)
        #pragma unroll
        for (int ks = 0; ks < 8; ++ks)
            bfr[nt][ks] = *(const f16x8*)(BT +
                (size_t)(nw + nt * 16 + l15) * 256 + ks * 32 + quad * 8);

    float bgv[2] = {0.f, 0.f};
    if (mode == 1) { bgv[0] = bg[nw + l15]; bgv[1] = bg[nw + 16 + l15]; }

    const int row_base = blk * 512;            // 16 panels x 32 rows per block

    f32x4 acc[2][2];
    #pragma unroll
    for (int mt = 0; mt < 2; ++mt)
        #pragma unroll
        for (int nt = 0; nt < 2; ++nt) acc[mt][nt] = (f32x4){0.f, 0.f, 0.f, 0.f};

    // Stage panel (32 rows x 256 fp32 = 32 KB) into A_s[buf], source-swizzled:
    // physical chunk (r, c) holds logical chunk (r, (c&~7)|((c&7)^(r&7))).
    auto stage = [&](int panel, int buf) {
        const int row0 = row_base + panel * 32;
        #pragma unroll
        for (int j = 0; j < 8; ++j) {
            const int p = tid + j * 256;       // 16B-chunk id 0..2047
            const int r = p >> 6, c = p & 63;
            const int cl = (c & ~7) | ((c & 7) ^ (r & 7));
            gload16(A + (size_t)(row0 + r) * 256 + cl * 4, &A_s[buf][p * 4]);
        }
    };

    stage(0, 0);
    __syncthreads();

    for (int i = 0; i < 16; ++i) {
        if (i < 15) stage(i + 1, (i + 1) & 1);
        const int buf = i & 1;

        #pragma unroll
        for (int ks = 0; ks < 8; ++ks) {
            f16x8 af[2];
            #pragma unroll
            for (int mt = 0; mt < 2; ++mt) {
                const int r  = mt * 16 + l15;
                const int x0 = ks * 8 + ((quad * 2 + 0) ^ (r & 7));
                const int x1 = ks * 8 + ((quad * 2 + 1) ^ (r & 7));
                const f32x4 a0 = *(const f32x4*)&A_s[buf][(r * 64 + x0) * 4];
                const f32x4 a1 = *(const f32x4*)&A_s[buf][(r * 64 + x1) * 4];
                f16x8 v;
                v[0] = (_Float16)a0[0]; v[1] = (_Float16)a0[1];
                v[2] = (_Float16)a0[2]; v[3] = (_Float16)a0[3];
                v[4] = (_Float16)a1[0]; v[5] = (_Float16)a1[1];
                v[6] = (_Float16)a1[2]; v[7] = (_Float16)a1[3];
                af[mt] = v;
            }
            #pragma unroll
            for (int mt = 0; mt < 2; ++mt)
                #pragma unroll
                for (int nt = 0; nt < 2; ++nt)
                    acc[mt][nt] = __builtin_amdgcn_mfma_f32_16x16x32_f16(
                        af[mt], bfr[nt][ks], acc[mt][nt], 0, 0, 0);
        }

        // Epilogue for this panel, then re-zero acc.
        const int row0 = row_base + i * 32;
        if (mode == 3) {
            #pragma unroll
            for (int mt = 0; mt < 2; ++mt) {
                #pragma unroll
                for (int nt = 0; nt < 2; ++nt) {
                    const int col  = nw + nt * 16 + l15;
                    const int rowg = row0 + mt * 16 + quad * 4;
                    const int nn = rowg >> 9, kpos = rowg & 511;
                    f16x4 st;
                    #pragma unroll
                    for (int reg = 0; reg < 4; ++reg) st[reg] = (_Float16)acc[mt][nt][reg];
                    *(f16x4*)&ovT[((size_t)(nn * 256 + col)) * 512 + kpos] = st;
                }
            }
        } else {
            _Float16* C = (mode == 0) ? oq : (mode == 1) ? og : ok;
            #pragma unroll
            for (int mt = 0; mt < 2; ++mt) {
                #pragma unroll
                for (int nt = 0; nt < 2; ++nt) {
                    const int col  = nw + nt * 16 + l15;
                    const int rowg = row0 + mt * 16 + quad * 4;
                    #pragma unroll
                    for (int reg = 0; reg < 4; ++reg) {
                        float x = acc[mt][nt][reg];
                        if (mode == 0) x *= 0.17677669529663689f;
                        if (mode == 1) { x += bgv[nt]; x = 1.0f / (1.0f + __expf(-x)); }
                        C[(size_t)(rowg + reg) * HIDDIM + col] = (_Float16)x;
                    }
                }
            }
        }
        #pragma unroll
        for (int mt = 0; mt < 2; ++mt)
            #pragma unroll
            for (int nt = 0; nt < 2; ++nt) acc[mt][nt] = (f32x4){0.f, 0.f, 0.f, 0.f};

        __syncthreads();   // publishes panel i+1 (vmcnt drain overlapped above)
    }
}

// ---------------------------------------------------------------------------
// Output projection GEMM (fp16 in, fp32 out + bias). Both operands staged via
// async global_load_lds, double-buffered, ONE barrier per K-step. (unchanged)
// ---------------------------------------------------------------------------
__global__ __launch_bounds__(256, 2) void gemm_mfma_kernel(
    const _Float16* __restrict__ Ain, const _Float16* __restrict__ BT,
    const float* __restrict__ bias, float* __restrict__ Cout)
{
    __shared__ __attribute__((aligned(16))) _Float16 A_s[2][128 * 64];
    __shared__ __attribute__((aligned(16))) _Float16 B_s[2][128 * 64];
    const int m0 = blockIdx.x * 128, n0 = blockIdx.y * 128;
    const int tid = threadIdx.x;
    const int lane = tid & 63, w = tid >> 6;
    const int l15 = lane & 15, quad = lane >> 4;
    const int mw = (w & 1) * 64, nw = (w >> 1) * 64;

    f32x4 acc[4][4];
    #pragma unroll
    for (int mt = 0; mt < 4; ++mt)
        #pragma unroll
        for (int nt = 0; nt < 4; ++nt) acc[mt][nt] = (f32x4){0.f, 0.f, 0.f, 0.f};

    #pragma unroll
    for (int j = 0; j < 4; ++j) {
        const int p = tid + j * 256;
        const int r = p >> 3;
        const int lc = (p & 7) ^ (r & 7);
        gload16(Ain + (size_t)(m0 + r) * CIN + lc * 8, &A_s[0][p * 8]);
        gload16(BT  + (size_t)(n0 + r) * CIN + lc * 8, &B_s[0][p * 8]);
    }
    __syncthreads();

    int buf = 0;
    for (int kk = 0; kk < 4; ++kk) {
        if (kk < 3) {
            const int k0n = (kk + 1) * 64;
            #pragma unroll
            for (int j = 0; j < 4; ++j) {
                const int p = tid + j * 256;
                const int r = p >> 3;
                const int lc = (p & 7) ^ (r & 7);
                gload16(Ain + (size_t)(m0 + r) * CIN + k0n + lc * 8, &A_s[buf ^ 1][p * 8]);
                gload16(BT  + (size_t)(n0 + r) * CIN + k0n + lc * 8, &B_s[buf ^ 1][p * 8]);
            }
        }
        #pragma unroll
        for (int ks = 0; ks < 2; ++ks) {
            f16x8 af[4], bf[4];
            #pragma unroll
            for (int mt = 0; mt < 4; ++mt) {
                const int arow = mw + mt * 16 + l15;
                const int ac = (ks * 4 + quad) ^ (arow & 7);
                af[mt] = *(const f16x8*)&A_s[buf][arow * 64 + ac * 8];
            }
            #pragma unroll
            for (int nt = 0; nt < 4; ++nt) {
                const int brow = nw + nt * 16 + l15;
                const int bc = (ks * 4 + quad) ^ (brow & 7);
                bf[nt] = *(const f16x8*)&B_s[buf][brow * 64 + bc * 8];
            }
            #pragma unroll
            for (int mt = 0; mt < 4; ++mt)
                #pragma unroll
                for (int nt = 0; nt < 4; ++nt)
                    acc[mt][nt] = __builtin_amdgcn_mfma_f32_16x16x32_f16(
                        af[mt], bf[nt], acc[mt][nt], 0, 0, 0);
        }
        if (kk < 3) { __syncthreads(); buf ^= 1; }
    }

    #pragma unroll
    for (int mt = 0; mt < 4; ++mt) {
        #pragma unroll
        for (int nt = 0; nt < 4; ++nt) {
            const int col = n0 + nw + nt * 16 + l15;
            const int rowb = m0 + mw + mt * 16 + quad * 4;
            #pragma unroll
            for (int reg = 0; reg < 4; ++reg) {
                const float x = acc[mt][nt][reg] + bias[col];
                Cout[(size_t)(rowb + reg) * HIDDIM + col] = x;
            }
        }
    }
}

// ---------------------------------------------------------------------------
// MFMA flash attention — UNCHANGED.
// ---------------------------------------------------------------------------
__global__ __launch_bounds__(256, 4) void attn_kernel(
    const _Float16* __restrict__ qb, const _Float16* __restrict__ kb,
    const _Float16* __restrict__ vT, const _Float16* __restrict__ gb,
    _Float16* __restrict__ ob,
    const float* __restrict__ bias_mask, const float* __restrict__ bp_frag)
{
    __shared__ _Float16 k_s[128][40];    // 80B rows ≡ 20 banks mod 32
    __shared__ _Float16 v_s[32][136];    // [c][k], 272B rows ≡ 4 banks mod 32

    const int n    = blockIdx.x;
    const int h    = blockIdx.y;
    const int q0   = blockIdx.z * 128;
    const int tid  = threadIdx.x;
    const int lane = tid & 63;
    const int wq   = tid >> 6;            // wave id: q-band = wq*32
    const int l15  = lane & 15;
    const int quad = lane >> 4;

    f16x8 qf[2];
    #pragma unroll
    for (int qt = 0; qt < 2; ++qt)
        qf[qt] = *(const f16x8*)(qb +
            (size_t)(n * QLEN + q0 + wq * 32 + qt * 16 + l15) * HIDDIM + h * CH + quad * 8);

    const float* bpf = bp_frag +
        ((size_t)(h * 32 + blockIdx.z * 8 + wq * 2) * 32) * 256 + lane * 4;
    const float* bmb = bias_mask + n * KLEN + quad * 4;

    f32x4 o_acc[2][2];
    float l_lane[2] = {0.f, 0.f};
    #pragma unroll
    for (int qt = 0; qt < 2; ++qt)
        #pragma unroll
        for (int ct = 0; ct < 2; ++ct) o_acc[qt][ct] = (f32x4){0.f, 0.f, 0.f, 0.f};

    const f32x4 z4 = (f32x4){0.f, 0.f, 0.f, 0.f};

    for (int ch = 0; ch < 4; ++ch) {
        __syncthreads();
        #pragma unroll
        for (int i = 0; i < 2; ++i) {
            const int idx = tid + i * 256;
            const int r = idx >> 2, c8 = idx & 3;
            *(uint4*)&k_s[r][c8 * 8] = *(const uint4*)
                (kb + (size_t)(n * KLEN + ch * 128 + r) * HIDDIM + h * CH + c8 * 8);
            const int vr = idx >> 4, vs = idx & 15;
            *(uint4*)&v_s[vr][vs * 8] = *(const uint4*)
                (vT + ((size_t)(n * HEADS + h) * CH + vr) * KLEN + ch * 128 + vs * 8);
        }
        __syncthreads();

        #pragma unroll
        for (int kt = 0; kt < 8; ++kt) {
            const int kti = ch * 8 + kt;
            const f16x8 kf = *(const f16x8*)&k_s[kt * 16 + l15][quad * 8];
            const f32x4 s0 = __builtin_amdgcn_mfma_f32_16x16x32_f16(kf, qf[0], z4, 0, 0, 0);
            const f32x4 s1 = __builtin_amdgcn_mfma_f32_16x16x32_f16(kf, qf[1], z4, 0, 0, 0);
            const float4 bm = *(const float4*)(bmb + ch * 128 + kt * 16);
            const f16x4 bv0 = *(const f16x4*)&v_s[l15][kt * 16 + quad * 4];
            const f16x4 bv1 = *(const f16x4*)&v_s[16 + l15][kt * 16 + quad * 4];
            #pragma unroll
            for (int qt = 0; qt < 2; ++qt) {
                const f32x4 s = qt ? s1 : s0;
                const float4 bp = *(const float4*)(bpf + ((size_t)qt * 32 + kti) * 256);
                const float p0 = __expf(s[0] + bm.x + bp.x - 4.0f);
                const float p1 = __expf(s[1] + bm.y + bp.y - 4.0f);
                const float p2 = __expf(s[2] + bm.z + bp.z - 4.0f);
                const float p3 = __expf(s[3] + bm.w + bp.w - 4.0f);
                l_lane[qt] += (p0 + p1) + (p2 + p3);
                union { f16x4 v; fp16x2 h[2]; } u;
                u.h[0] = __builtin_amdgcn_cvt_pkrtz(p0, p1);
                u.h[1] = __builtin_amdgcn_cvt_pkrtz(p2, p3);
                o_acc[qt][0] = __builtin_amdgcn_mfma_f32_16x16x16f16(u.v, bv0, o_acc[qt][0], 0, 0, 0);
                o_acc[qt][1] = __builtin_amdgcn_mfma_f32_16x16x16f16(u.v, bv1, o_acc[qt][1], 0, 0, 0);
            }
        }
    }

    float invl[2][4];
    #pragma unroll
    for (int qt = 0; qt < 2; ++qt) {
        float lf = l_lane[qt];
        lf += __shfl_xor(lf, 16);
        lf += __shfl_xor(lf, 32);
        #pragma unroll
        for (int reg = 0; reg < 4; ++reg)
            invl[qt][reg] = 1.0f / __shfl(lf, quad * 4 + reg);
    }

    #pragma unroll
    for (int qt = 0; qt < 2; ++qt) {
        #pragma unroll
        for (int ct = 0; ct < 2; ++ct) {
            #pragma unroll
            for (int reg = 0; reg < 4; ++reg) {
                const int row = q0 + wq * 32 + qt * 16 + quad * 4 + reg;
                const size_t idx = (size_t)(n * QLEN + row) * HIDDIM + h * CH + ct * 16 + l15;
                const float g = (float)gb[idx];
                ob[idx] = (_Float16)(o_acc[qt][ct][reg] * invl[qt][reg] * g);
            }
        }
    }
}

// ---------------------------------------------------------------------------
// Launch: wcast + bpfrag -> flatmm projections (q,g,k,v->vT) -> attention ->
// output GEMM.
// Workspace: 5 x 16.8 MB fp16 + 0.66 MB weights + 8.4 MB bp_frag ≈ 93 MB
// ---------------------------------------------------------------------------
extern "C" void kernel_launch(void* const* d_in, const int* in_sizes, int n_in,
                              void* d_out, int out_size, void* d_ws, size_t ws_size,
                              hipStream_t stream)
{
    const float* q_x       = (const float*)d_in[0];
    const float* k_x       = (const float*)d_in[1];
    const float* v_x       = (const float*)d_in[2];
    const float* bias_mask = (const float*)d_in[3];
    const float* bias_pair = (const float*)d_in[4];
    const float* wq        = (const float*)d_in[5];
    const float* wk        = (const float*)d_in[6];
    const float* wv        = (const float*)d_in[7];
    const float* wg        = (const float*)d_in[8];
    const float* bg        = (const float*)d_in[9];
    const float* wo        = (const float*)d_in[10];
    const float* bo        = (const float*)d_in[11];
    float* out = (float*)d_out;

    const size_t BUF = (size_t)M_TOTAL * HIDDIM;   // 8388608 elems
    _Float16* ws_q  = (_Float16*)d_ws;
    _Float16* ws_k  = ws_q + BUF;
    _Float16* ws_vT = ws_k + BUF;
    _Float16* ws_g  = ws_vT + BUF;
    _Float16* ws_o  = ws_g + BUF;
    _Float16* wT    = ws_o + BUF;                  // 5 x 256*256 fp16
    float*    bpf   = (float*)(wT + 5 * 65536);    // 8 x 512 x 512 fp32 frag-ordered

    // slab order q, g, k, v, o
    wcast_kernel<<<dim3(4, 4, 5), 256, 0, stream>>>(wq, wg, wk, wv, wo, wT);
    bpfrag_kernel<<<dim3(8, 8, 8), 256, 0, stream>>>(bias_pair, bpf);

    proj_gemm_kernel<<<dim3(512), 256, 0, stream>>>(
        q_x, k_x, v_x, wT, bg, ws_q, ws_k, ws_vT, ws_g);

    attn_kernel<<<dim3(NSEQ, HEADS, QLEN / 128), 256, 0, stream>>>(
        ws_q, ws_k, ws_vT, ws_g, ws_o, bias_mask, bpf);

    gemm_mfma_kernel<<<dim3(M_TOTAL / 128, 2), 256, 0, stream>>>(
        ws_o, wT + 4 * 65536, bo, out);
}